// Round 9
// baseline (594.928 us; speedup 1.0000x reference)
//
#include <hip/hip_runtime.h>
#include <hip/hip_bf16.h>

typedef short short8 __attribute__((ext_vector_type(8)));
typedef float f32x4 __attribute__((ext_vector_type(4)));

#define CIN   128
#define COUT  128
#define HH    32
#define WW    32
#define LTOT  1024
#define KKT   9
#define KDIM  1152

// LDS per block: A dbuf 2 x 16KB at [0,32768); B 6 rows x 32 cols x 256B = 48KB
#define ABUF  16384
#define BOFF  32768
#define SMEM_BYTES 81920

// ---- tiny prep: wt[o*1152 + kk*128 + c] = bf16(w[(o*128+c)*9 + kk]) ----
__global__ void prep_w_kernel(const float* __restrict__ w, __hip_bfloat16* __restrict__ wt) {
  int i = blockIdx.x * 256 + threadIdx.x;
  int o = i / KDIM;
  int r = i - o * KDIM;
  int kk = r >> 7, c = r & 127;
  wt[i] = __float2bfloat16(w[(o * CIN + c) * KKT + kk]);
}

__device__ __forceinline__ void gld16(const char* g, char* l) {
  __builtin_amdgcn_global_load_lds(
      (const __attribute__((address_space(1))) void*)g,
      (__attribute__((address_space(3))) void*)l, 16, 0, 0);
}

// ABLATION TEMPLATE (r8 structure). V: 0=FULL, 1=no-MFMA, 2=no-ds_read,
// 3=skeleton (no ds, no MFMA), 4=FULL without setprio.
// grid = 512*R; replicas compute identical values (deterministic races).
template<int V>
__global__ __launch_bounds__(256, 2)
void conv_abl(const float* __restrict__ x,
              const __hip_bfloat16* __restrict__ wt,
              const float* __restrict__ mask,
              const float* __restrict__ bias,
              float* __restrict__ out) {
  extern __shared__ char smem[];
  const int tid = threadIdx.x;
  const int rb  = blockIdx.x & 511;
  const int bid = (rb & 7) * 64 + (rb >> 3);   // XCD swizzle, bijective on 512
  const int b  = bid >> 4;
  const int o0 = (bid & 1) << 6;
  const int l0 = ((bid >> 1) & 7) << 7;
  const int h0 = ((bid >> 1) & 7) << 2;

  const int lane = tid & 63, wid = tid >> 6;
  const int lr = lane & 15, lg = lane >> 4;
  const int n_base = wid << 5;
  const int hl = wid;

  float mvA[9], mvB[9];
  {
    const float* mr = mask + l0 + n_base + lr;
#pragma unroll
    for (int kk = 0; kk < 9; ++kk) { mvA[kk] = mr[kk * LTOT]; mvB[kk] = mr[kk * LTOT + 16]; }
  }

  // B-build (all variants): fused transpose+convert, two passes
  const int wv = tid & 31, cg = tid >> 5;
  const float* xb = x + (size_t)b * CIN * LTOT;
  for (int p = 0; p < 2; ++p) {
    const int q = cg + p * 8;
    char* bdst = smem + BOFF + wv * 256 + ((q ^ (wv & 15)) << 4);
    float fr[6][8];
#pragma unroll
    for (int r = 0; r < 6; ++r) {
      const int hg = h0 - 1 + r;
      if ((unsigned)hg < (unsigned)HH) {
        const float* s = xb + (size_t)q * 8 * LTOT + hg * WW + wv;
#pragma unroll
        for (int j = 0; j < 8; ++j) fr[r][j] = s[(size_t)j * LTOT];
      }
    }
    asm volatile("s_waitcnt vmcnt(0)" ::: "memory");
#pragma unroll
    for (int r = 0; r < 6; ++r) {
      const int hg = h0 - 1 + r;
      short8 v = (short8){0, 0, 0, 0, 0, 0, 0, 0};
      if ((unsigned)hg < (unsigned)HH) {
#pragma unroll
        for (int j = 0; j < 8; ++j)
          v[j] = (short)__builtin_bit_cast(unsigned short, __float2bfloat16(fr[r][j]));
      }
      *(short8*)(bdst + r * 8192) = v;
    }
  }
#pragma unroll
  for (int kk = 0; kk < 9; ++kk)
    asm volatile("" : "+v"(mvA[kk]), "+v"(mvB[kk]));

  // dummy MFMA operand for V2/V3 (deterministic, pinned against folding)
  short8 dumm;
#pragma unroll
  for (int j = 0; j < 8; ++j) dumm[j] = (short)(0x3f80 | ((tid + j) & 7));
  {
    f32x4 dp = __builtin_bit_cast(f32x4, dumm);
    asm volatile("" : "+v"(dp));
    dumm = __builtin_bit_cast(short8, dp);
  }

  // A staging (all variants)
  const int t4 = tid >> 4, ch = tid & 15;
  const int cx = ((ch ^ (t4 & 15)) << 4);
  int asrc[4];
#pragma unroll
  for (int r = 0; r < 4; ++r) asrc[r] = (r * 16 + t4) * 2304 + cx;
  const char* wtc = (const char*)wt + (size_t)o0 * 2304;
  auto stageA = [&](int kk) {
    const char* s = wtc + kk * 256;
    char* d = smem + (kk & 1) * ABUF + tid * 16;
#pragma unroll
    for (int r = 0; r < 4; ++r) gld16(s + asrc[r], d + r * 4096);
  };
  stageA(0);
  stageA(1);
  asm volatile("s_waitcnt lgkmcnt(0)" ::: "memory");

  f32x4 acc[4][2], par[4][2];
#pragma unroll
  for (int mi = 0; mi < 4; ++mi)
#pragma unroll
    for (int nj = 0; nj < 2; ++nj) {
      acc[mi][nj] = (f32x4){0.f, 0.f, 0.f, 0.f};
      par[mi][nj] = (f32x4){0.f, 0.f, 0.f, 0.f};
    }

#pragma unroll
  for (int kk = 0; kk < 9; ++kk) {
    if (kk < 8) asm volatile("s_waitcnt vmcnt(4)" ::: "memory");
    else        asm volatile("s_waitcnt vmcnt(0)" ::: "memory");
    __builtin_amdgcn_s_barrier();

    const char* A = smem + (kk & 1) * ABUF;
    const int di = (kk * 11) >> 5;
    const int dj = kk - 3 * di;
    const int col0 = lr + dj - 1;
    const int col1 = 16 + lr + dj - 1;
    const bool v0 = (unsigned)col0 < (unsigned)WW;
    const bool v1 = (unsigned)col1 < (unsigned)WW;
    const int cc0 = v0 ? col0 : 0;
    const int cc1 = v1 ? col1 : 0;
    const char* B0 = smem + BOFF + (hl + di) * 8192 + cc0 * 256;
    const char* B1 = smem + BOFF + (hl + di) * 8192 + cc1 * 256;
    const int x0 = cc0 & 15, x1 = cc1 & 15;
    const char* A0 = A + (lr)      * 256;
    const char* A1 = A + (16 + lr) * 256;
    const char* A2 = A + (32 + lr) * 256;
    const char* A3 = A + (48 + lr) * 256;

    if constexpr (V != 4) __builtin_amdgcn_s_setprio(1);
#pragma unroll
    for (int ks = 0; ks < 4; ++ks) {
      const int q = ks * 4 + lg;
      short8 af0, af1, af2, af3, bf0, bf1;
      if constexpr (V == 0 || V == 1 || V == 4) {
        af0 = *(const short8*)(A0 + ((q ^ lr) << 4));
        af1 = *(const short8*)(A1 + ((q ^ lr) << 4));
        af2 = *(const short8*)(A2 + ((q ^ lr) << 4));
        af3 = *(const short8*)(A3 + ((q ^ lr) << 4));
        bf0 = *(const short8*)(B0 + ((q ^ x0) << 4));
        bf1 = *(const short8*)(B1 + ((q ^ x1) << 4));
      } else {
        af0 = dumm; af1 = dumm; af2 = dumm; af3 = dumm; bf0 = dumm; bf1 = dumm;
      }
      if constexpr (V == 1) {
        // keep the ds_reads live without MFMA (rule #17)
        f32x4 s0 = __builtin_bit_cast(f32x4, af0);
        f32x4 s1 = __builtin_bit_cast(f32x4, af1);
        f32x4 s2 = __builtin_bit_cast(f32x4, af2);
        f32x4 s3 = __builtin_bit_cast(f32x4, af3);
        f32x4 s4 = __builtin_bit_cast(f32x4, bf0);
        f32x4 s5 = __builtin_bit_cast(f32x4, bf1);
        asm volatile("" :: "v"(s0), "v"(s1), "v"(s2), "v"(s3), "v"(s4), "v"(s5));
      }
      if constexpr (V == 0 || V == 2 || V == 4) {
        par[0][0] = __builtin_amdgcn_mfma_f32_16x16x32_bf16(af0, bf0, par[0][0], 0, 0, 0);
        par[1][0] = __builtin_amdgcn_mfma_f32_16x16x32_bf16(af1, bf0, par[1][0], 0, 0, 0);
        par[2][0] = __builtin_amdgcn_mfma_f32_16x16x32_bf16(af2, bf0, par[2][0], 0, 0, 0);
        par[3][0] = __builtin_amdgcn_mfma_f32_16x16x32_bf16(af3, bf0, par[3][0], 0, 0, 0);
        par[0][1] = __builtin_amdgcn_mfma_f32_16x16x32_bf16(af0, bf1, par[0][1], 0, 0, 0);
        par[1][1] = __builtin_amdgcn_mfma_f32_16x16x32_bf16(af1, bf1, par[1][1], 0, 0, 0);
        par[2][1] = __builtin_amdgcn_mfma_f32_16x16x32_bf16(af2, bf1, par[2][1], 0, 0, 0);
        par[3][1] = __builtin_amdgcn_mfma_f32_16x16x32_bf16(af3, bf1, par[3][1], 0, 0, 0);
      }
    }
    if constexpr (V != 4) __builtin_amdgcn_s_setprio(0);

    const float m0 = v0 ? mvA[kk] : 0.f;
    const float m1 = v1 ? mvB[kk] : 0.f;
#pragma unroll
    for (int mi = 0; mi < 4; ++mi)
#pragma unroll
      for (int rr = 0; rr < 4; ++rr) {
        acc[mi][0][rr] += m0 * par[mi][0][rr];  par[mi][0][rr] = 0.f;
        acc[mi][1][rr] += m1 * par[mi][1][rr];  par[mi][1][rr] = 0.f;
      }

    asm volatile("s_waitcnt lgkmcnt(0)" ::: "memory");
    __builtin_amdgcn_s_barrier();
    if (kk <= 6) stageA(kk + 2);
  }

  float* outb = out + (size_t)b * COUT * LTOT + (size_t)o0 * LTOT + l0;
#pragma unroll
  for (int mi = 0; mi < 4; ++mi) {
#pragma unroll
    for (int rr = 0; rr < 4; ++rr) {
      int o = mi * 16 + lg * 4 + rr;
      float bv = bias[o0 + o];
      outb[(size_t)o * LTOT + n_base      + lr] = acc[mi][0][rr] + bv;
      outb[(size_t)o * LTOT + n_base + 16 + lr] = acc[mi][1][rr] + bv;
    }
  }
}

extern "C" void kernel_launch(void* const* d_in, const int* in_sizes, int n_in,
                              void* d_out, int out_size, void* d_ws, size_t ws_size,
                              hipStream_t stream) {
  const float* x    = (const float*)d_in[0];
  const float* mask = (const float*)d_in[1];
  const float* w    = (const float*)d_in[2];
  const float* bias = (const float*)d_in[3];
  float* out = (float*)d_out;
  __hip_bfloat16* wt = (__hip_bfloat16*)d_ws;

  (void)hipFuncSetAttribute(reinterpret_cast<const void*>(&conv_abl<0>),
                            hipFuncAttributeMaxDynamicSharedMemorySize, SMEM_BYTES);
  (void)hipFuncSetAttribute(reinterpret_cast<const void*>(&conv_abl<1>),
                            hipFuncAttributeMaxDynamicSharedMemorySize, SMEM_BYTES);
  (void)hipFuncSetAttribute(reinterpret_cast<const void*>(&conv_abl<2>),
                            hipFuncAttributeMaxDynamicSharedMemorySize, SMEM_BYTES);
  (void)hipFuncSetAttribute(reinterpret_cast<const void*>(&conv_abl<3>),
                            hipFuncAttributeMaxDynamicSharedMemorySize, SMEM_BYTES);
  (void)hipFuncSetAttribute(reinterpret_cast<const void*>(&conv_abl<4>),
                            hipFuncAttributeMaxDynamicSharedMemorySize, SMEM_BYTES);

  prep_w_kernel<<<576, 256, 0, stream>>>(w, wt);

  // Ablation dispatches (8 replicas each so every variant clears the top-5
  // display threshold). Replicas write identical values -> deterministic.
  conv_abl<0><<<4096, 256, SMEM_BYTES, stream>>>(x, wt, mask, bias, out);  // FULL
  conv_abl<4><<<4096, 256, SMEM_BYTES, stream>>>(x, wt, mask, bias, out);  // FULL - setprio
  conv_abl<1><<<4096, 256, SMEM_BYTES, stream>>>(x, wt, mask, bias, out);  // no MFMA (out=bias)
  conv_abl<2><<<4096, 256, SMEM_BYTES, stream>>>(x, wt, mask, bias, out);  // no ds_read
  conv_abl<3><<<4096, 256, SMEM_BYTES, stream>>>(x, wt, mask, bias, out);  // skeleton
  // Final correct output:
  conv_abl<0><<<512, 256, SMEM_BYTES, stream>>>(x, wt, mask, bias, out);
}

// Round 10
// 25.985 us; speedup vs baseline: 22.8950x; 22.8950x over previous
//
#include <hip/hip_runtime.h>
#include <hip/hip_fp16.h>

typedef _Float16 half8 __attribute__((ext_vector_type(8)));
typedef float f32x4 __attribute__((ext_vector_type(4)));

#define CIN   128
#define COUT  128
#define HH    32
#define WW    32
#define LTOT  1024
#define KKT   9
#define KDIM  1152

// LDS: A dbuf 2 x 32KB at [0,65536); B 6 rows x 32 cols x 256B = 48KB at [65536,114688)
#define ABUF  32768
#define BOFF  65536
#define SMEM_BYTES 114688

// ---- tiny prep: wt[o*1152 + kk*128 + c] = f16(w[(o*128+c)*9 + kk]) ----
__global__ void prep_w_kernel(const float* __restrict__ w, _Float16* __restrict__ wt) {
  int i = blockIdx.x * 256 + threadIdx.x;     // 576 blocks -> covers 147456 exactly
  int o = i / KDIM;
  int r = i - o * KDIM;
  int kk = r >> 7, c = r & 127;
  wt[i] = (_Float16)w[(o * CIN + c) * KKT + kk];
}

__device__ __forceinline__ void gld16(const char* g, char* l) {
  __builtin_amdgcn_global_load_lds(
      (const __attribute__((address_space(1))) void*)g,
      (__attribute__((address_space(3))) void*)l, 16, 0, 0);
}

// 256 blocks x 256 threads (4 waves, 2m x 2n, wave tile 64o x 64l, mfma 16x16x32 f16).
// Block tile 128(o) x 128(l), one image-b, 4 h-rows. Mask folded into B-FRAGMENTS
// via v_pk_mul_f16 (no par accumulator, no fold pass). B tile resident (fp16,
// built in-kernel from f32 x). A streamed per tap, double-buffered, gld16 +
// counted vmcnt. LDS chunk swizzle: slot = chunk ^ (row_or_col & 15).
__global__ __launch_bounds__(256, 1)
void conv_mfma_kernel(const float* __restrict__ x,
                      const _Float16* __restrict__ wt,
                      const float* __restrict__ mask,
                      const float* __restrict__ bias,
                      float* __restrict__ out) {
  extern __shared__ char smem[];
  const int tid = threadIdx.x;
  int bid = blockIdx.x;
  bid = (bid & 7) * 32 + (bid >> 3);     // XCD swizzle, bijective (256 % 8 == 0)
  const int b  = bid >> 3;
  const int l0 = (bid & 7) << 7;         // 128 l per block
  const int h0 = (bid & 7) << 2;         // 4 h-rows per block

  const int lane = tid & 63, wid = tid >> 6;
  const int lr = lane & 15, lg = lane >> 4;
  const int mw = (wid >> 1) << 6;        // wave m base {0,64}
  const int nw = (wid & 1) << 6;         // wave n base {0,64}

  // ---- mask preload: 36 scalars per lane (kk x nj) ----
  float mv[9][4];
  {
    const float* mr = mask + l0 + nw + lr;
#pragma unroll
    for (int kk = 0; kk < 9; ++kk)
#pragma unroll
      for (int nj = 0; nj < 4; ++nj)
        mv[kk][nj] = mr[kk * LTOT + nj * 16];
  }

  // ---- B-build: x[b][c][hg][w] -> fp16 tile, two passes (reg pressure) ----
  const int wv = tid & 31, cg = tid >> 5;          // col (w), chunk-group 0..7
  const float* xb = x + (size_t)b * CIN * LTOT;
  for (int p = 0; p < 2; ++p) {
    const int q = cg + p * 8;                      // 16-B chunk 0..15 (8 c's)
    char* bdst = smem + BOFF + wv * 256 + ((q ^ (wv & 15)) << 4);
    float fr[6][8];
#pragma unroll
    for (int r = 0; r < 6; ++r) {
      const int hg = h0 - 1 + r;
      if ((unsigned)hg < (unsigned)HH) {           // block-uniform branch
        const float* s = xb + (size_t)q * 8 * LTOT + hg * WW + wv;
#pragma unroll
        for (int j = 0; j < 8; ++j) fr[r][j] = s[(size_t)j * LTOT];
      }
    }
    asm volatile("s_waitcnt vmcnt(0)" ::: "memory");
#pragma unroll
    for (int r = 0; r < 6; ++r) {
      const int hg = h0 - 1 + r;
      half8 v = (half8){0, 0, 0, 0, 0, 0, 0, 0};
      if ((unsigned)hg < (unsigned)HH) {
#pragma unroll
        for (int j = 0; j < 8; ++j) v[j] = (_Float16)fr[r][j];
      }
      *(half8*)(bdst + r * 8192) = v;
    }
  }
#pragma unroll
  for (int kk = 0; kk < 9; ++kk)
#pragma unroll
    for (int nj = 0; nj < 4; ++nj)
      asm volatile("" : "+v"(mv[kk][nj]));         // keep masks resident past drains

  // ---- A staging: 8 gld16/thread per tap (32 KB = 128 rows x 256 B) ----
  const int t4 = tid >> 4, ch = tid & 15;
  const int cx = (ch ^ (t4 & 15)) << 4;
  int asrc[8];
#pragma unroll
  for (int r = 0; r < 8; ++r) asrc[r] = (r * 16 + t4) * 2304 + cx;
  const char* wtc = (const char*)wt;
  auto stageA = [&](int kk) {
    const char* s = wtc + kk * 256;
    char* d = smem + (kk & 1) * ABUF + tid * 16;
#pragma unroll
    for (int r = 0; r < 8; ++r) gld16(s + asrc[r], d + r * 4096);
  };
  stageA(0);
  stageA(1);
  asm volatile("s_waitcnt lgkmcnt(0)" ::: "memory");   // my B ds_writes done

  f32x4 acc[4][4];                                 // [mi][nj], 64 VGPR
#pragma unroll
  for (int mi = 0; mi < 4; ++mi)
#pragma unroll
    for (int nj = 0; nj < 4; ++nj)
      acc[mi][nj] = (f32x4){0.f, 0.f, 0.f, 0.f};

#pragma unroll
  for (int kk = 0; kk < 9; ++kk) {
    if (kk < 8) asm volatile("s_waitcnt vmcnt(8)" ::: "memory");  // A(kk) done, A(kk+1) in flight
    else        asm volatile("s_waitcnt vmcnt(0)" ::: "memory");
    __builtin_amdgcn_s_barrier();

    const char* A = smem + (kk & 1) * ABUF;
    const int di = (kk * 11) >> 5;               // kk/3
    const int dj = kk - 3 * di;

    // per-nj B geometry + masked fp16 scalar (OOB tap -> m=0, garbage*0)
    const char* Bp[4];
    int xk[4];
    _Float16 mh[4];
#pragma unroll
    for (int nj = 0; nj < 4; ++nj) {
      const int wb = ((nj & 1) << 4) + lr + dj - 1;
      const bool vld = (unsigned)wb < (unsigned)WW;
      const int wc = vld ? wb : 0;
      const int hrow = (nw >> 5) + (nj >> 1) + di;   // 0..5
      Bp[nj] = smem + BOFF + hrow * 8192 + wc * 256;
      xk[nj] = wc & 15;
      mh[nj] = (_Float16)(vld ? mv[kk][nj] : 0.f);
    }
    const char* A0 = A + (mw + lr) * 256;

#pragma unroll
    for (int ks = 0; ks < 4; ++ks) {
      const int q = ks * 4 + lg;
      half8 a0 = *(const half8*)(A0 +     0 + ((q ^ lr) << 4));
      half8 a1 = *(const half8*)(A0 +  4096 + ((q ^ lr) << 4));
      half8 a2 = *(const half8*)(A0 +  8192 + ((q ^ lr) << 4));
      half8 a3 = *(const half8*)(A0 + 12288 + ((q ^ lr) << 4));
      half8 b0 = *(const half8*)(Bp[0] + ((q ^ xk[0]) << 4)) * mh[0];
      half8 b1 = *(const half8*)(Bp[1] + ((q ^ xk[1]) << 4)) * mh[1];
      half8 b2 = *(const half8*)(Bp[2] + ((q ^ xk[2]) << 4)) * mh[2];
      half8 b3 = *(const half8*)(Bp[3] + ((q ^ xk[3]) << 4)) * mh[3];
      acc[0][0] = __builtin_amdgcn_mfma_f32_16x16x32_f16(a0, b0, acc[0][0], 0, 0, 0);
      acc[1][0] = __builtin_amdgcn_mfma_f32_16x16x32_f16(a1, b0, acc[1][0], 0, 0, 0);
      acc[2][0] = __builtin_amdgcn_mfma_f32_16x16x32_f16(a2, b0, acc[2][0], 0, 0, 0);
      acc[3][0] = __builtin_amdgcn_mfma_f32_16x16x32_f16(a3, b0, acc[3][0], 0, 0, 0);
      acc[0][1] = __builtin_amdgcn_mfma_f32_16x16x32_f16(a0, b1, acc[0][1], 0, 0, 0);
      acc[1][1] = __builtin_amdgcn_mfma_f32_16x16x32_f16(a1, b1, acc[1][1], 0, 0, 0);
      acc[2][1] = __builtin_amdgcn_mfma_f32_16x16x32_f16(a2, b1, acc[2][1], 0, 0, 0);
      acc[3][1] = __builtin_amdgcn_mfma_f32_16x16x32_f16(a3, b1, acc[3][1], 0, 0, 0);
      acc[0][2] = __builtin_amdgcn_mfma_f32_16x16x32_f16(a0, b2, acc[0][2], 0, 0, 0);
      acc[1][2] = __builtin_amdgcn_mfma_f32_16x16x32_f16(a1, b2, acc[1][2], 0, 0, 0);
      acc[2][2] = __builtin_amdgcn_mfma_f32_16x16x32_f16(a2, b2, acc[2][2], 0, 0, 0);
      acc[3][2] = __builtin_amdgcn_mfma_f32_16x16x32_f16(a3, b2, acc[3][2], 0, 0, 0);
      acc[0][3] = __builtin_amdgcn_mfma_f32_16x16x32_f16(a0, b3, acc[0][3], 0, 0, 0);
      acc[1][3] = __builtin_amdgcn_mfma_f32_16x16x32_f16(a1, b3, acc[1][3], 0, 0, 0);
      acc[2][3] = __builtin_amdgcn_mfma_f32_16x16x32_f16(a2, b3, acc[2][3], 0, 0, 0);
      acc[3][3] = __builtin_amdgcn_mfma_f32_16x16x32_f16(a3, b3, acc[3][3], 0, 0, 0);
    }

    asm volatile("s_waitcnt lgkmcnt(0)" ::: "memory");  // my buf reads retired
    __builtin_amdgcn_s_barrier();
    if (kk <= 6) stageA(kk + 2);                        // refill buffer just read
  }

  // ---- epilogue: C/D layout col(l)=lane&15, row(o)=(lane>>4)*4+rr ----
  float* outb = out + (size_t)b * COUT * LTOT + l0;
#pragma unroll
  for (int mi = 0; mi < 4; ++mi) {
#pragma unroll
    for (int rr = 0; rr < 4; ++rr) {
      const int o = mw + mi * 16 + lg * 4 + rr;
      const float bv = bias[o];
      float* orow = outb + (size_t)o * LTOT + nw + lr;
#pragma unroll
      for (int nj = 0; nj < 4; ++nj)
        orow[nj * 16] = acc[mi][nj][rr] + bv;
    }
  }
}

extern "C" void kernel_launch(void* const* d_in, const int* in_sizes, int n_in,
                              void* d_out, int out_size, void* d_ws, size_t ws_size,
                              hipStream_t stream) {
  const float* x    = (const float*)d_in[0];
  const float* mask = (const float*)d_in[1];
  const float* w    = (const float*)d_in[2];
  const float* bias = (const float*)d_in[3];
  float* out = (float*)d_out;
  _Float16* wt = (_Float16*)d_ws;

  (void)hipFuncSetAttribute(reinterpret_cast<const void*>(conv_mfma_kernel),
                            hipFuncAttributeMaxDynamicSharedMemorySize, SMEM_BYTES);

  prep_w_kernel<<<576, 256, 0, stream>>>(w, wt);
  conv_mfma_kernel<<<256, 256, SMEM_BYTES, stream>>>(x, wt, mask, bias, out);
}

// Round 11
// 25.308 us; speedup vs baseline: 23.5071x; 1.0267x over previous
//
#include <hip/hip_runtime.h>
#include <hip/hip_fp16.h>

typedef _Float16 half8 __attribute__((ext_vector_type(8)));
typedef float f32x4 __attribute__((ext_vector_type(4)));

#define CIN   128
#define COUT  128
#define HH    32
#define WW    32
#define LTOT  1024
#define KKT   9
#define KDIM  1152

// LDS: A dbuf 2 x 32KB at [0,65536); B 6 rows x 32 cols x 256B = 48KB at [65536,114688)
// after the loop, [0,69632) is reused as the K-split reduction buffer.
#define ABUF  32768
#define BOFF  65536
#define SMEM_BYTES 114688

// ---- tiny prep: wt[o*1152 + kk*128 + c] = f16(w[(o*128+c)*9 + kk]) ----
__global__ void prep_w_kernel(const float* __restrict__ w, _Float16* __restrict__ wt) {
  int i = blockIdx.x * 256 + threadIdx.x;     // 576 blocks -> covers 147456 exactly
  int o = i / KDIM;
  int r = i - o * KDIM;
  int kk = r >> 7, c = r & 127;
  wt[i] = (_Float16)w[(o * CIN + c) * KKT + kk];
}

__device__ __forceinline__ void gld16(const char* g, char* l) {
  __builtin_amdgcn_global_load_lds(
      (const __attribute__((address_space(1))) void*)g,
      (__attribute__((address_space(3))) void*)l, 16, 0, 0);
}

// 256 blocks x 512 threads (8 waves = 2 waves/SIMD). Block tile 128(o) x 128(l).
// K-SPLIT: waves 0-3 (kh=0) and 4-7 (kh=1) compute the SAME 2x2 grid of 64x64
// wave tiles, each over half the c-range per tap; LDS read volume per CU is
// unchanged vs r10, but 2 waves/SIMD now cross-hide latency. Final K-reduction
// through LDS. Mask folded into B-fragments (v_pk_mul_f16). B tile resident;
// A streamed per tap, double-buffered, gld16 + counted vmcnt. Chunk swizzle:
// slot = chunk ^ (row_or_col & 15) on both sides.
__global__ __launch_bounds__(512, 2)
void conv_mfma_kernel(const float* __restrict__ x,
                      const _Float16* __restrict__ wt,
                      const float* __restrict__ mask,
                      const float* __restrict__ bias,
                      float* __restrict__ out) {
  extern __shared__ char smem[];
  const int tid = threadIdx.x;
  int bid = blockIdx.x;
  bid = (bid & 7) * 32 + (bid >> 3);     // XCD swizzle, bijective (256 % 8 == 0)
  const int b  = bid >> 3;
  const int l0 = (bid & 7) << 7;         // 128 l per block
  const int h0 = (bid & 7) << 2;         // 4 h-rows per block

  const int lane = tid & 63, wid = tid >> 6;
  const int lr = lane & 15, lg = lane >> 4;
  const int kh = wid >> 2;               // K-half: 0 -> c 0..63, 1 -> c 64..127
  const int wq = wid & 3;
  const int mw = (wq >> 1) << 6;         // wave m base {0,64}
  const int nw = (wq & 1) << 6;          // wave n base {0,64}

  // ---- mask preload: 36 scalars per lane (kk x nj) ----
  float mv[9][4];
  {
    const float* mr = mask + l0 + nw + lr;
#pragma unroll
    for (int kk = 0; kk < 9; ++kk)
#pragma unroll
      for (int nj = 0; nj < 4; ++nj)
        mv[kk][nj] = mr[kk * LTOT + nj * 16];
  }

  // ---- B-build: x[b][c][hg][w] -> fp16 tile, single pass (512 threads) ----
  const int wv = tid & 31, q16 = tid >> 5;         // col (w), 16-B chunk 0..15
  char* bdst = smem + BOFF + wv * 256 + ((q16 ^ (wv & 15)) << 4);
  const float* xb = x + (size_t)b * CIN * LTOT;
  {
    float fr[6][8];
#pragma unroll
    for (int r = 0; r < 6; ++r) {
      const int hg = h0 - 1 + r;
      if ((unsigned)hg < (unsigned)HH) {           // block-uniform branch
        const float* s = xb + (size_t)q16 * 8 * LTOT + hg * WW + wv;
#pragma unroll
        for (int j = 0; j < 8; ++j) fr[r][j] = s[(size_t)j * LTOT];
      }
    }
    asm volatile("s_waitcnt vmcnt(0)" ::: "memory");
#pragma unroll
    for (int r = 0; r < 6; ++r) {
      const int hg = h0 - 1 + r;
      half8 v = (half8){0, 0, 0, 0, 0, 0, 0, 0};
      if ((unsigned)hg < (unsigned)HH) {
#pragma unroll
        for (int j = 0; j < 8; ++j) v[j] = (_Float16)fr[r][j];
      }
      *(half8*)(bdst + r * 8192) = v;
    }
  }
#pragma unroll
  for (int kk = 0; kk < 9; ++kk)
#pragma unroll
    for (int nj = 0; nj < 4; ++nj)
      asm volatile("" : "+v"(mv[kk][nj]));         // keep masks resident past drains

  // ---- A staging: 4 gld16/thread per tap (32 KB = 128 rows x 256 B) ----
  const int t4 = tid >> 4, ch = tid & 15;
  const int cx = (ch ^ (t4 & 15)) << 4;
  int asrc[4];
#pragma unroll
  for (int r = 0; r < 4; ++r) asrc[r] = (r * 32 + t4) * 2304 + cx;
  const char* wtc = (const char*)wt;
  auto stageA = [&](int kk) {
    const char* s = wtc + kk * 256;
    char* d = smem + (kk & 1) * ABUF + tid * 16;
#pragma unroll
    for (int r = 0; r < 4; ++r) gld16(s + asrc[r], d + r * 8192);
  };
  stageA(0);
  stageA(1);
  asm volatile("s_waitcnt lgkmcnt(0)" ::: "memory");   // my B ds_writes done

  f32x4 acc[4][4];                                 // [mi][nj], 64 VGPR
#pragma unroll
  for (int mi = 0; mi < 4; ++mi)
#pragma unroll
    for (int nj = 0; nj < 4; ++nj)
      acc[mi][nj] = (f32x4){0.f, 0.f, 0.f, 0.f};

#pragma unroll
  for (int kk = 0; kk < 9; ++kk) {
    if (kk < 8) asm volatile("s_waitcnt vmcnt(4)" ::: "memory");  // A(kk) done, A(kk+1) in flight
    else        asm volatile("s_waitcnt vmcnt(0)" ::: "memory");
    __builtin_amdgcn_s_barrier();

    const char* A = smem + (kk & 1) * ABUF;
    const int di = (kk * 11) >> 5;               // kk/3
    const int dj = kk - 3 * di;

    // per-nj B geometry + masked fp16 scalar (OOB tap -> m=0, garbage*0)
    const char* Bp[4];
    int xk[4];
    _Float16 mh[4];
#pragma unroll
    for (int nj = 0; nj < 4; ++nj) {
      const int wb = ((nj & 1) << 4) + lr + dj - 1;
      const bool vld = (unsigned)wb < (unsigned)WW;
      const int wc = vld ? wb : 0;
      const int hrow = (nw >> 5) + (nj >> 1) + di;   // 0..5
      Bp[nj] = smem + BOFF + hrow * 8192 + wc * 256;
      xk[nj] = wc & 15;
      mh[nj] = (_Float16)(vld ? mv[kk][nj] : 0.f);
    }
    const char* A0 = A + (mw + lr) * 256;

    __builtin_amdgcn_s_setprio(1);
#pragma unroll
    for (int s = 0; s < 2; ++s) {
      const int q = (kh * 2 + s) * 4 + lg;       // K-half chunks
      half8 a0 = *(const half8*)(A0 +     0 + ((q ^ lr) << 4));
      half8 a1 = *(const half8*)(A0 +  4096 + ((q ^ lr) << 4));
      half8 a2 = *(const half8*)(A0 +  8192 + ((q ^ lr) << 4));
      half8 a3 = *(const half8*)(A0 + 12288 + ((q ^ lr) << 4));
      half8 b0 = *(const half8*)(Bp[0] + ((q ^ xk[0]) << 4)) * mh[0];
      half8 b1 = *(const half8*)(Bp[1] + ((q ^ xk[1]) << 4)) * mh[1];
      half8 b2 = *(const half8*)(Bp[2] + ((q ^ xk[2]) << 4)) * mh[2];
      half8 b3 = *(const half8*)(Bp[3] + ((q ^ xk[3]) << 4)) * mh[3];
      acc[0][0] = __builtin_amdgcn_mfma_f32_16x16x32_f16(a0, b0, acc[0][0], 0, 0, 0);
      acc[1][0] = __builtin_amdgcn_mfma_f32_16x16x32_f16(a1, b0, acc[1][0], 0, 0, 0);
      acc[2][0] = __builtin_amdgcn_mfma_f32_16x16x32_f16(a2, b0, acc[2][0], 0, 0, 0);
      acc[3][0] = __builtin_amdgcn_mfma_f32_16x16x32_f16(a3, b0, acc[3][0], 0, 0, 0);
      acc[0][1] = __builtin_amdgcn_mfma_f32_16x16x32_f16(a0, b1, acc[0][1], 0, 0, 0);
      acc[1][1] = __builtin_amdgcn_mfma_f32_16x16x32_f16(a1, b1, acc[1][1], 0, 0, 0);
      acc[2][1] = __builtin_amdgcn_mfma_f32_16x16x32_f16(a2, b1, acc[2][1], 0, 0, 0);
      acc[3][1] = __builtin_amdgcn_mfma_f32_16x16x32_f16(a3, b1, acc[3][1], 0, 0, 0);
      acc[0][2] = __builtin_amdgcn_mfma_f32_16x16x32_f16(a0, b2, acc[0][2], 0, 0, 0);
      acc[1][2] = __builtin_amdgcn_mfma_f32_16x16x32_f16(a1, b2, acc[1][2], 0, 0, 0);
      acc[2][2] = __builtin_amdgcn_mfma_f32_16x16x32_f16(a2, b2, acc[2][2], 0, 0, 0);
      acc[3][2] = __builtin_amdgcn_mfma_f32_16x16x32_f16(a3, b2, acc[3][2], 0, 0, 0);
      acc[0][3] = __builtin_amdgcn_mfma_f32_16x16x32_f16(a0, b3, acc[0][3], 0, 0, 0);
      acc[1][3] = __builtin_amdgcn_mfma_f32_16x16x32_f16(a1, b3, acc[1][3], 0, 0, 0);
      acc[2][3] = __builtin_amdgcn_mfma_f32_16x16x32_f16(a2, b3, acc[2][3], 0, 0, 0);
      acc[3][3] = __builtin_amdgcn_mfma_f32_16x16x32_f16(a3, b3, acc[3][3], 0, 0, 0);
    }
    __builtin_amdgcn_s_setprio(0);

    asm volatile("s_waitcnt lgkmcnt(0)" ::: "memory");  // my buf reads retired
    __builtin_amdgcn_s_barrier();
    if (kk <= 6) stageA(kk + 2);                        // refill buffer just read
  }

  // ---- K-split reduction through LDS (region [0, 69632), loop is done) ----
  char* red = smem + wq * 17408 + lane * 272;
  if (kh == 1) {
#pragma unroll
    for (int mi = 0; mi < 4; ++mi)
#pragma unroll
      for (int nj = 0; nj < 4; ++nj)
        *(f32x4*)(red + (mi * 4 + nj) * 16) = acc[mi][nj];
  }
  asm volatile("s_waitcnt lgkmcnt(0)" ::: "memory");
  __builtin_amdgcn_s_barrier();

  if (kh == 0) {
#pragma unroll
    for (int mi = 0; mi < 4; ++mi)
#pragma unroll
      for (int nj = 0; nj < 4; ++nj) {
        f32x4 p = *(const f32x4*)(red + (mi * 4 + nj) * 16);
        acc[mi][nj].x += p.x; acc[mi][nj].y += p.y;
        acc[mi][nj].z += p.z; acc[mi][nj].w += p.w;
      }

    // ---- epilogue: C/D layout col(l)=lane&15, row(o)=(lane>>4)*4+rr ----
    float* outb = out + (size_t)b * COUT * LTOT + l0;
#pragma unroll
    for (int mi = 0; mi < 4; ++mi) {
#pragma unroll
      for (int rr = 0; rr < 4; ++rr) {
        const int o = mw + mi * 16 + lg * 4 + rr;
        const float bv = bias[o];
        float* orow = outb + (size_t)o * LTOT + nw + lr;
#pragma unroll
        for (int nj = 0; nj < 4; ++nj)
          orow[nj * 16] = acc[mi][nj][rr] + bv;
      }
    }
  }
}

extern "C" void kernel_launch(void* const* d_in, const int* in_sizes, int n_in,
                              void* d_out, int out_size, void* d_ws, size_t ws_size,
                              hipStream_t stream) {
  const float* x    = (const float*)d_in[0];
  const float* mask = (const float*)d_in[1];
  const float* w    = (const float*)d_in[2];
  const float* bias = (const float*)d_in[3];
  float* out = (float*)d_out;
  _Float16* wt = (_Float16*)d_ws;

  (void)hipFuncSetAttribute(reinterpret_cast<const void*>(conv_mfma_kernel),
                            hipFuncAttributeMaxDynamicSharedMemorySize, SMEM_BYTES);

  prep_w_kernel<<<576, 256, 0, stream>>>(w, wt);
  conv_mfma_kernel<<<256, 512, SMEM_BYTES, stream>>>(x, wt, mask, bias, out);
}

// Round 12
// 24.980 us; speedup vs baseline: 23.8161x; 1.0131x over previous
//
#include <hip/hip_runtime.h>
#include <hip/hip_fp16.h>

typedef _Float16 half8 __attribute__((ext_vector_type(8)));
typedef float f32x4 __attribute__((ext_vector_type(4)));

#define CIN   128
#define COUT  128
#define HH    32
#define WW    32
#define LTOT  1024
#define KKT   9
#define KDIM  1152

// LDS: B tile 6 rows x 32 cols x 256B = 48KB at [0, 49152).
// After the loop (post-barrier) [0, 69632) is reused as the K-split
// reduction buffer. No A staging in LDS at all.
#define SMEM_BYTES 69632

// ---- prep: fragment-ordered weights ----
// wt3[q*1024 + o*8 + j] = f16(w[(o*128 + c)*9 + kk]),  q = kk*16 + (c>>3), j = c&7.
// A wave's 16B fragment (o-rows consecutive, fixed q) is contiguous per 16 lanes.
__global__ void prep_w_kernel(const float* __restrict__ w, _Float16* __restrict__ wt) {
  int i = blockIdx.x * 256 + threadIdx.x;   // 576 blocks cover 147456 = 144*1024
  int q = i >> 10;                          // 0..143
  int o = (i >> 3) & 127;
  int j = i & 7;
  int kk = q >> 4;
  int c  = ((q & 15) << 3) + j;
  wt[i] = (_Float16)w[(o * CIN + c) * KKT + kk];
}

// 256 blocks x 512 threads (8 waves). Block tile 128(o) x 128(l), one image-b.
// K-SPLIT: waves 0-3 (kh=0) / 4-7 (kh=1) each do half of c per tap over the
// same 2x2 grid of 64x64 wave tiles; LDS reduction at the end.
// A-fragments: DIRECT global->VGPR from wt3 (L1/L2-resident, no LDS, no
// barriers, no vmcnt choreography). B: fp16 tile resident in LDS, built once.
// The 9-tap loop is barrier-free; compiler pipelines the unrolled body.
__global__ __launch_bounds__(512, 2)
void conv_mfma_kernel(const float* __restrict__ x,
                      const _Float16* __restrict__ wt,
                      const float* __restrict__ mask,
                      const float* __restrict__ bias,
                      float* __restrict__ out) {
  extern __shared__ char smem[];
  const int tid = threadIdx.x;
  int bid = blockIdx.x;
  bid = (bid & 7) * 32 + (bid >> 3);     // XCD swizzle, bijective (256 % 8 == 0)
  const int b  = bid >> 3;
  const int l0 = (bid & 7) << 7;         // 128 l per block
  const int h0 = (bid & 7) << 2;         // 4 h-rows per block

  const int lane = tid & 63, wid = tid >> 6;
  const int lr = lane & 15, lg = lane >> 4;
  const int kh = wid >> 2;               // K-half: 0 -> c 0..63, 1 -> c 64..127
  const int wq = wid & 3;
  const int mw = (wq >> 1) << 6;         // wave m base {0,64}
  const int nw = (wq & 1) << 6;          // wave n base {0,64}

  // ---- mask preload: 36 scalars per lane (kk x nj) ----
  float mv[9][4];
  {
    const float* mr = mask + l0 + nw + lr;
#pragma unroll
    for (int kk = 0; kk < 9; ++kk)
#pragma unroll
      for (int nj = 0; nj < 4; ++nj)
        mv[kk][nj] = mr[kk * LTOT + nj * 16];
  }

  // ---- B-build: x[b][c][hg][w] -> fp16 tile, single pass (512 threads) ----
  const int wv = tid & 31, q16 = tid >> 5;         // col (w), 16-B chunk 0..15
  char* bdst = smem + wv * 256 + ((q16 ^ (wv & 15)) << 4);
  const float* xb = x + (size_t)b * CIN * LTOT;
  {
    float fr[6][8];
#pragma unroll
    for (int r = 0; r < 6; ++r) {
      const int hg = h0 - 1 + r;
      if ((unsigned)hg < (unsigned)HH) {           // block-uniform branch
        const float* s = xb + (size_t)q16 * 8 * LTOT + hg * WW + wv;
#pragma unroll
        for (int j = 0; j < 8; ++j) fr[r][j] = s[(size_t)j * LTOT];
      }
    }
    asm volatile("s_waitcnt vmcnt(0)" ::: "memory");
#pragma unroll
    for (int r = 0; r < 6; ++r) {
      const int hg = h0 - 1 + r;
      half8 v = (half8){0, 0, 0, 0, 0, 0, 0, 0};
      if ((unsigned)hg < (unsigned)HH) {
#pragma unroll
        for (int j = 0; j < 8; ++j) v[j] = (_Float16)fr[r][j];
      }
      *(half8*)(bdst + r * 8192) = v;
    }
  }
#pragma unroll
  for (int kk = 0; kk < 9; ++kk)
#pragma unroll
    for (int nj = 0; nj < 4; ++nj)
      asm volatile("" : "+v"(mv[kk][nj]));         // keep masks resident past drain
  __syncthreads();                                 // B tile visible to all waves

  // per-lane A base: addr(q, o) = (q*1024 + o*8)*2 bytes; q = qb + lg,
  // o = mw + mi*16 + lr  ->  abase + qb*2048 + mi*256 (qb, mi compile-time)
  const char* abase = (const char*)wt + lg * 2048 + (mw + lr) * 16;

  f32x4 acc[4][4];                                 // [mi][nj], 64 VGPR
#pragma unroll
  for (int mi = 0; mi < 4; ++mi)
#pragma unroll
    for (int nj = 0; nj < 4; ++nj)
      acc[mi][nj] = (f32x4){0.f, 0.f, 0.f, 0.f};

  // ---- barrier-free 9-tap loop ----
#pragma unroll
  for (int kk = 0; kk < 9; ++kk) {
    const int di = (kk * 11) >> 5;               // kk/3
    const int dj = kk - 3 * di;

    // per-nj B geometry + masked fp16 scalar (OOB tap -> m=0, garbage*0)
    const char* Bp[4];
    int xk[4];
    _Float16 mh[4];
#pragma unroll
    for (int nj = 0; nj < 4; ++nj) {
      const int wb = ((nj & 1) << 4) + lr + dj - 1;
      const bool vld = (unsigned)wb < (unsigned)WW;
      const int wc = vld ? wb : 0;
      const int hrow = (nw >> 5) + (nj >> 1) + di;   // 0..5
      Bp[nj] = smem + hrow * 8192 + wc * 256;
      xk[nj] = wc & 15;
      mh[nj] = (_Float16)(vld ? mv[kk][nj] : 0.f);
    }

    __builtin_amdgcn_s_setprio(1);
#pragma unroll
    for (int s = 0; s < 2; ++s) {
      const int qb = kk * 16 + (kh * 2 + s) * 4;   // compile-time per site... (kh uniform/wave)
      const char* ab = abase + qb * 2048;
      const int q = qb + lg;                       // B chunk index for this lg group
      half8 a0 = *(const half8*)(ab);
      half8 a1 = *(const half8*)(ab + 256);
      half8 a2 = *(const half8*)(ab + 512);
      half8 a3 = *(const half8*)(ab + 768);
      half8 b0 = *(const half8*)(Bp[0] + (((q & 15) ^ xk[0]) << 4)) * mh[0];
      half8 b1 = *(const half8*)(Bp[1] + (((q & 15) ^ xk[1]) << 4)) * mh[1];
      half8 b2 = *(const half8*)(Bp[2] + (((q & 15) ^ xk[2]) << 4)) * mh[2];
      half8 b3 = *(const half8*)(Bp[3] + (((q & 15) ^ xk[3]) << 4)) * mh[3];
      acc[0][0] = __builtin_amdgcn_mfma_f32_16x16x32_f16(a0, b0, acc[0][0], 0, 0, 0);
      acc[1][0] = __builtin_amdgcn_mfma_f32_16x16x32_f16(a1, b0, acc[1][0], 0, 0, 0);
      acc[2][0] = __builtin_amdgcn_mfma_f32_16x16x32_f16(a2, b0, acc[2][0], 0, 0, 0);
      acc[3][0] = __builtin_amdgcn_mfma_f32_16x16x32_f16(a3, b0, acc[3][0], 0, 0, 0);
      acc[0][1] = __builtin_amdgcn_mfma_f32_16x16x32_f16(a0, b1, acc[0][1], 0, 0, 0);
      acc[1][1] = __builtin_amdgcn_mfma_f32_16x16x32_f16(a1, b1, acc[1][1], 0, 0, 0);
      acc[2][1] = __builtin_amdgcn_mfma_f32_16x16x32_f16(a2, b1, acc[2][1], 0, 0, 0);
      acc[3][1] = __builtin_amdgcn_mfma_f32_16x16x32_f16(a3, b1, acc[3][1], 0, 0, 0);
      acc[0][2] = __builtin_amdgcn_mfma_f32_16x16x32_f16(a0, b2, acc[0][2], 0, 0, 0);
      acc[1][2] = __builtin_amdgcn_mfma_f32_16x16x32_f16(a1, b2, acc[1][2], 0, 0, 0);
      acc[2][2] = __builtin_amdgcn_mfma_f32_16x16x32_f16(a2, b2, acc[2][2], 0, 0, 0);
      acc[3][2] = __builtin_amdgcn_mfma_f32_16x16x32_f16(a3, b2, acc[3][2], 0, 0, 0);
      acc[0][3] = __builtin_amdgcn_mfma_f32_16x16x32_f16(a0, b3, acc[0][3], 0, 0, 0);
      acc[1][3] = __builtin_amdgcn_mfma_f32_16x16x32_f16(a1, b3, acc[1][3], 0, 0, 0);
      acc[2][3] = __builtin_amdgcn_mfma_f32_16x16x32_f16(a2, b3, acc[2][3], 0, 0, 0);
      acc[3][3] = __builtin_amdgcn_mfma_f32_16x16x32_f16(a3, b3, acc[3][3], 0, 0, 0);
    }
    __builtin_amdgcn_s_setprio(0);
  }

  // ---- K-split reduction through LDS (B region dead after this barrier) ----
  __syncthreads();
  char* red = smem + wq * 17408 + lane * 272;
  if (kh == 1) {
#pragma unroll
    for (int mi = 0; mi < 4; ++mi)
#pragma unroll
      for (int nj = 0; nj < 4; ++nj)
        *(f32x4*)(red + (mi * 4 + nj) * 16) = acc[mi][nj];
  }
  __syncthreads();

  if (kh == 0) {
#pragma unroll
    for (int mi = 0; mi < 4; ++mi)
#pragma unroll
      for (int nj = 0; nj < 4; ++nj) {
        f32x4 p = *(const f32x4*)(red + (mi * 4 + nj) * 16);
        acc[mi][nj].x += p.x; acc[mi][nj].y += p.y;
        acc[mi][nj].z += p.z; acc[mi][nj].w += p.w;
      }

    // ---- epilogue: C/D layout col(l)=lane&15, row(o)=(lane>>4)*4+rr ----
    float* outb = out + (size_t)b * COUT * LTOT + l0;
#pragma unroll
    for (int mi = 0; mi < 4; ++mi) {
#pragma unroll
      for (int rr = 0; rr < 4; ++rr) {
        const int o = mw + mi * 16 + lg * 4 + rr;
        const float bv = bias[o];
        float* orow = outb + (size_t)o * LTOT + nw + lr;
#pragma unroll
        for (int nj = 0; nj < 4; ++nj)
          orow[nj * 16] = acc[mi][nj][rr] + bv;
      }
    }
  }
}

extern "C" void kernel_launch(void* const* d_in, const int* in_sizes, int n_in,
                              void* d_out, int out_size, void* d_ws, size_t ws_size,
                              hipStream_t stream) {
  const float* x    = (const float*)d_in[0];
  const float* mask = (const float*)d_in[1];
  const float* w    = (const float*)d_in[2];
  const float* bias = (const float*)d_in[3];
  float* out = (float*)d_out;
  _Float16* wt = (_Float16*)d_ws;

  (void)hipFuncSetAttribute(reinterpret_cast<const void*>(conv_mfma_kernel),
                            hipFuncAttributeMaxDynamicSharedMemorySize, SMEM_BYTES);

  prep_w_kernel<<<576, 256, 0, stream>>>(w, wt);
  conv_mfma_kernel<<<256, 512, SMEM_BYTES, stream>>>(x, wt, mask, bias, out);
}